// Round 1
// baseline (871.655 us; speedup 1.0000x reference)
//
#include <hip/hip_runtime.h>

// Problem constants (from reference)
#define Bsz 16
#define Cc  256
#define Ll  4096
#define Pp  100
#define Qq  20
#define PQ  (Pp * Qq)     // 2000

typedef float f32x4 __attribute__((ext_vector_type(4)));

// ---------------------------------------------------------------------------
// NUMERICS CONTRACT (bit-exact vs numpy fp32 reference, validated previously):
//   a[b,p,l]: chain c=0..255 of a = fmaf(X[b,c,l], proj[p,c], a)      [fp32]
//   thr[p,q] = fadd(mn, fmul(fsub(mx,mn), (q+1)/21))                  [fp32,
//              separate roundings; (q+1)/21 correctly-rounded fp32 div]
//   cdf = popcount/4096 (exact dyadic fp32; atomic order irrelevant)
//
// STRUCTURE (R1 split): the fused kernel was latency-limited (10 waves/CU,
// grid-bound occupancy) and re-read X 10x. Split:
//   csf_proj:   a = X @ proj^T, X read from HBM exactly once, acc[100]/lane.
//               'a' stashed into set_out row (p*Q+0) — no workspace needed.
//   csf_thresh: 100 waves/CU pure store engine; reads stash, writes 20 rows.
//               The stash row (q=0) is read-then-overwritten by the SAME
//               thread that owns it -> no cross-thread hazard.
// ---------------------------------------------------------------------------

// grid (Ll/256, Bsz), block 256; lane owns one l. X read = 67 MB total, once.
__global__ __launch_bounds__(256) void csf_proj(
    const float* __restrict__ X,
    const float* __restrict__ proj,
    float* __restrict__ set_out) {
  const int l = blockIdx.x * 256 + threadIdx.x;
  const int b = blockIdx.y;
  const float* Xb = X + (size_t)b * Cc * Ll + l;

  float acc[Pp];
#pragma unroll
  for (int p = 0; p < Pp; p++) acc[p] = 0.0f;

  // c-chunks of 8 with one-chunk register prefetch: 8 independent coalesced
  // 256B wave-loads in flight while 800 FMAs issue (1 wave/SIMD here, so ILP
  // must hide the load latency).
  float x[8];
#pragma unroll
  for (int j = 0; j < 8; j++) x[j] = Xb[(size_t)j * Ll];

#pragma unroll 1
  for (int cc = 0; cc < Cc; cc += 8) {
    float xn[8];
    const bool more = (cc + 8 < Cc);
    if (more) {
#pragma unroll
      for (int j = 0; j < 8; j++) xn[j] = Xb[(size_t)(cc + 8 + j) * Ll];
    }
    // proj[p][cc..cc+7] is wave-uniform -> s_load_dwordx* ; FMA takes the
    // weight as the SGPR operand. Per-acc chain remains c-ascending (j inner).
#pragma unroll
    for (int p = 0; p < Pp; p++) {
      const float* pr = proj + (size_t)p * Cc + cc;
#pragma unroll
      for (int j = 0; j < 8; j++)
        acc[p] = __builtin_fmaf(x[j], pr[j], acc[p]);
    }
    if (more) {
#pragma unroll
      for (int j = 0; j < 8; j++) x[j] = xn[j];
    }
  }

  // stash a[b,p,l] into set_out[b][p*Qq + 0][l]; normal stores (want L2/L3
  // residency for csf_thresh's read; 26 MB fits L3 easily).
  float* ob = set_out + (size_t)b * PQ * Ll + l;
#pragma unroll
  for (int p = 0; p < Pp; p++)
    ob[(size_t)p * Qq * Ll] = acc[p];
}

// grid (Ll/1024, Pp, Bsz) = 6400 blocks, block 256; lane owns 4 consecutive l.
// 100 waves/CU -> deep store queue; writes are the roofline term (524 MB).
__global__ __launch_bounds__(256) void csf_thresh(
    const float* __restrict__ mn,
    const float* __restrict__ mx,
    float* __restrict__ cdf,       // zeroed before launch
    float* __restrict__ set_out) {
  const int lt  = blockIdx.x;                 // 0..3
  const int p   = blockIdx.y;                 // 0..99
  const int b   = blockIdx.z;
  const int tid = threadIdx.x;
  const int l0  = lt * 1024 + tid * 4;

  float* ob = set_out + (size_t)b * PQ * Ll + (size_t)p * Qq * Ll + l0;
  const f32x4 a = *(const f32x4*)ob;          // stash row (q=0) from csf_proj

  const float mnp = mn[p];
  const float mxp = mx[p];
  const float d   = __fsub_rn(mxp, mnp);      // fl(mx-mn)

  // fl((q+1)/21): compile-time IEEE-correctly-rounded fp32 division — bit
  // identical to np.arange(1..Q,f32)/f32(21) and to runtime __fdiv_rn.
  const float FR[Qq] = {
     1.0f/21.0f,  2.0f/21.0f,  3.0f/21.0f,  4.0f/21.0f,  5.0f/21.0f,
     6.0f/21.0f,  7.0f/21.0f,  8.0f/21.0f,  9.0f/21.0f, 10.0f/21.0f,
    11.0f/21.0f, 12.0f/21.0f, 13.0f/21.0f, 14.0f/21.0f, 15.0f/21.0f,
    16.0f/21.0f, 17.0f/21.0f, 18.0f/21.0f, 19.0f/21.0f, 20.0f/21.0f };

  const bool lane0 = ((tid & 63) == 0);
  float* cp = cdf + (size_t)b * PQ + (size_t)p * Qq;

#pragma unroll
  for (int q = 0; q < Qq; q++) {
    // fl(mn + fl(d*frac)) — separate roundings, no FMA contraction
    const float thr = __fadd_rn(mnp, __fmul_rn(d, FR[q]));
    const bool b0 = a.x < thr;
    const bool b1 = a.y < thr;
    const bool b2 = a.z < thr;
    const bool b3 = a.w < thr;
    f32x4 o;
    o.x = b0 ? 1.0f : 0.0f;
    o.y = b1 ? 1.0f : 0.0f;
    o.z = b2 ? 1.0f : 0.0f;
    o.w = b3 ? 1.0f : 0.0f;
    // streaming, never re-read -> non-temporal. q=0 overwrites the stash row
    // AFTER this thread's read (in-thread data dependency orders it).
    __builtin_nontemporal_store(o, (f32x4*)(ob + (size_t)q * Ll));
    // per-wave count: 4 ballots (one per sub-l bit)
    const int cnt = __popcll(__ballot(b0)) + __popcll(__ballot(b1))
                  + __popcll(__ballot(b2)) + __popcll(__ballot(b3));
    if (lane0) {
      // exact: every term is a multiple of 2^-12, sums are dyadic <= 1
      atomicAdd(cp + q, (float)cnt * (1.0f / (float)Ll));
    }
  }
}

// ---------------------------------------------------------------------------
extern "C" void kernel_launch(void* const* d_in, const int* in_sizes, int n_in,
                              void* d_out, int out_size, void* d_ws, size_t ws_size,
                              hipStream_t stream) {
  const float* X    = (const float*)d_in[0];   // [B,C,L]
  const float* proj = (const float*)d_in[1];   // [P,C]
  const float* mn   = (const float*)d_in[2];   // [P]
  const float* mx   = (const float*)d_in[3];   // [P]

  float* cdf     = (float*)d_out;              // [B, P*Q]
  float* set_out = cdf + (size_t)Bsz * PQ;     // [B, P*Q, L]

  // zero cdf for atomic accumulation (128 KB, ~2 us)
  (void)hipMemsetAsync(cdf, 0, (size_t)Bsz * PQ * sizeof(float), stream);

  csf_proj<<<dim3(Ll / 256, Bsz), 256, 0, stream>>>(X, proj, set_out);
  csf_thresh<<<dim3(Ll / 1024, Pp, Bsz), 256, 0, stream>>>(mn, mx, cdf, set_out);
}

// Round 2
// 754.961 us; speedup vs baseline: 1.1546x; 1.1546x over previous
//
#include <hip/hip_runtime.h>

// Problem constants (from reference)
#define Bsz 16
#define Cc  256
#define Ll  4096
#define Pp  100
#define Qq  20
#define PQ  (Pp * Qq)     // 2000

#define LT   64           // l-tile per block (one l per lane)
#define CCH  64           // c-chunk staged in LDS at a time
#define PW   25           // p's per wave (4 waves x 25 = 100)

typedef float f32x4 __attribute__((ext_vector_type(4)));

// ---------------------------------------------------------------------------
// NUMERICS CONTRACT (bit-exact vs numpy fp32 reference, validated R0/R1):
//   a[b,p,l]: chain c=0..255 of a = fmaf(X[b,c,l], proj[p,c], a)      [fp32,
//             strictly c-ascending per accumulator]
//   thr[p,q] = fadd(mn, fmul(fsub(mx,mn), (q+1)/21))                  [fp32,
//             separate roundings; (q+1)/21 compile-time correctly-rounded]
//   cdf = popcount/4096; all partials are multiples of 2^-12, sums <= 1 are
//         exactly representable -> atomic order irrelevant, bit-exact.
//
// STRUCTURE (R2): R1's csf_proj spilled (acc[100] vs 64-VGPR cap -> scratch
// bound, 344 us, VALUBusy 6.7%). Fix: LDS-tile X (16 KB c-chunks), wave owns
// 25 p's -> acc[25] fits registers. Threshold+store+cdf fused in-register:
// no stash round-trip, no second kernel. X read from HBM exactly once.
// ---------------------------------------------------------------------------
__global__ __launch_bounds__(256, 4) void csf_fused(
    const float* __restrict__ X,
    const float* __restrict__ proj,
    const float* __restrict__ mn,
    const float* __restrict__ mx,
    float* __restrict__ cdf,        // [B, P*Q], zeroed before launch
    float* __restrict__ set_out) {  // [B, P*Q, L]
  __shared__ float xs[CCH][LT];     // 16 KB

  const int b    = blockIdx.y;
  const int l0   = blockIdx.x * LT;
  const int tid  = threadIdx.x;
  const int wave = tid >> 6;
  const int lane = tid & 63;
  const int p0   = __builtin_amdgcn_readfirstlane(wave * PW);  // wave-uniform

  // staging geometry: 16 threads cover one 64-float c-row (f32x4 each);
  // 256 threads cover 16 c-rows per pass, 4 passes per 64-c chunk.
  const int lsub = (tid & 15) * 4;
  const int crow = tid >> 4;                       // 0..15
  const float* Xg = X + (size_t)b * Cc * Ll + l0 + lsub;

  float acc[PW];
#pragma unroll
  for (int i = 0; i < PW; i++) acc[i] = 0.0f;

#pragma unroll 1
  for (int ch = 0; ch < Cc; ch += CCH) {
    if (ch) __syncthreads();        // previous chunk fully consumed
#pragma unroll
    for (int cc = 0; cc < CCH; cc += 16) {
      *(f32x4*)&xs[cc + crow][lsub] =
          *(const f32x4*)(Xg + (size_t)(ch + cc + crow) * Ll);
    }
    __syncthreads();
    // compute: x broadcast-read from LDS (stride 4B: 2 lanes/bank = free),
    // weights are wave-uniform -> scalar loads feeding v_fmac SGPR operand.
#pragma unroll 4
    for (int c = 0; c < CCH; c++) {
      const float x = xs[c][lane];
#pragma unroll
      for (int i = 0; i < PW; i++)
        acc[i] = __builtin_fmaf(x, proj[(size_t)(p0 + i) * Cc + ch + c], acc[i]);
    }
  }

  // fl((q+1)/21): compile-time IEEE-correctly-rounded fp32 division — bit
  // identical to np.arange(1..Q,f32)/np.float32(21).
  const float FR[Qq] = {
     1.0f/21.0f,  2.0f/21.0f,  3.0f/21.0f,  4.0f/21.0f,  5.0f/21.0f,
     6.0f/21.0f,  7.0f/21.0f,  8.0f/21.0f,  9.0f/21.0f, 10.0f/21.0f,
    11.0f/21.0f, 12.0f/21.0f, 13.0f/21.0f, 14.0f/21.0f, 15.0f/21.0f,
    16.0f/21.0f, 17.0f/21.0f, 18.0f/21.0f, 19.0f/21.0f, 20.0f/21.0f };

  // threshold + streaming store + cdf. Wave store = 64 lanes x 4B = 256 B
  // contiguous = 4 full 64B lines -> TCC write-combines; non-temporal keeps
  // L2 for X/proj. Ballot/popcount gives exact per-wave count.
  float* ob = set_out + (size_t)b * PQ * Ll + l0 + lane;
  float* cb = cdf + (size_t)b * PQ;
  const bool lane0 = (lane == 0);

#pragma unroll 1
  for (int i = 0; i < PW; i++) {
    const int p = p0 + i;
    const float mnp = mn[p];
    const float d   = __fsub_rn(mx[p], mnp);       // fl(mx-mn)
    float* obp = ob + (size_t)p * Qq * Ll;
#pragma unroll
    for (int q = 0; q < Qq; q++) {
      // fl(mn + fl(d*frac)) — separate roundings, no FMA contraction
      const float thr = __fadd_rn(mnp, __fmul_rn(d, FR[q]));
      const bool bb = acc[i] < thr;
      __builtin_nontemporal_store(bb ? 1.0f : 0.0f, obp + (size_t)q * Ll);
      const int cnt = __popcll(__ballot(bb));
      if (lane0) {
        // exact: every term is a multiple of 2^-12, sums are dyadic <= 1
        atomicAdd(cb + (size_t)p * Qq + q, (float)cnt * (1.0f / (float)Ll));
      }
    }
  }
}

// ---------------------------------------------------------------------------
extern "C" void kernel_launch(void* const* d_in, const int* in_sizes, int n_in,
                              void* d_out, int out_size, void* d_ws, size_t ws_size,
                              hipStream_t stream) {
  const float* X    = (const float*)d_in[0];   // [B,C,L]
  const float* proj = (const float*)d_in[1];   // [P,C]
  const float* mn   = (const float*)d_in[2];   // [P]
  const float* mx   = (const float*)d_in[3];   // [P]

  float* cdf     = (float*)d_out;              // [B, P*Q]
  float* set_out = cdf + (size_t)Bsz * PQ;     // [B, P*Q, L]

  // zero cdf for atomic accumulation (128 KB, ~2 us)
  (void)hipMemsetAsync(cdf, 0, (size_t)Bsz * PQ * sizeof(float), stream);

  csf_fused<<<dim3(Ll / LT, Bsz), 256, 0, stream>>>(X, proj, mn, mx, cdf, set_out);
}

// Round 3
// 727.618 us; speedup vs baseline: 1.1980x; 1.0376x over previous
//
#include <hip/hip_runtime.h>

// Problem constants (from reference)
#define Bsz 16
#define Cc  256
#define Ll  4096
#define Pp  100
#define Qq  20
#define PQ  (Pp * Qq)     // 2000

#define PW   25           // p's per wave (acc[25][4] = 100 VGPRs)
#define LT   256          // l-span per block; lane owns 4 consecutive l
#define CG   8            // c-group register-prefetch depth
#define NPG  2            // p-groups in grid.y (block covers 2 waves x 25 = 50 p)

typedef float f32x4 __attribute__((ext_vector_type(4)));

// ---------------------------------------------------------------------------
// NUMERICS CONTRACT (bit-exact vs numpy fp32 reference, validated R0-R2,
// absmax == 0.0 every round):
//   a[b,p,l]: chain c=0..255 of a = fmaf(X[b,c,l], proj[p,c], a)      [fp32,
//             strictly c-ascending per accumulator: cc outer asc, j inner asc]
//   fr[q]  = __fdiv_rn(q+1, 21)  (IEEE correctly-rounded, == np divide)
//   thr    = fadd(mn, fmul(fsub(mx,mn), fr))  [separate roundings, no FMA]
//   cdf    = popcount/4096; every term a multiple of 2^-12, dyadic sums <= 1
//            are exact in fp32 -> atomic order irrelevant, bit-exact.
//
// STRUCTURE (R3): R2's VGPR_Count=28 exposed acc[] homed in SCRATCH — the
// store loop's `#pragma unroll 1 for(i)` indexed acc[i] at runtime (rule #20),
// so every compute FMA paid a scratch round-trip (VALUBusy 21%, +53MB write
// traffic). Fix: EVERY acc/mnp/dd/cnt index is compile-time (i-loops fully
// unrolled; only q and cc loops are rolled, and they never index arrays).
// Also restored R0's proven store geometry: lane owns 4 consecutive l ->
// f32x4 nontemporal stores (1KB/wave-instr), 4 ballots merged -> 512K atomics
// total (R2 had 256B stores + 2M atomics). No LDS, no barriers: wave1 reads
// the same X lines as wave0 -> L1 hits; p-group pair re-reads X (<=2x HBM,
// +10us) to double the grid for scheduling slack.
// ---------------------------------------------------------------------------
__global__ __launch_bounds__(128, 1) void csf_fused(
    const float* __restrict__ X,
    const float* __restrict__ proj,
    const float* __restrict__ mn,
    const float* __restrict__ mx,
    float* __restrict__ cdf,        // [B, P*Q], zeroed before launch
    float* __restrict__ set_out) {  // [B, P*Q, L]
  const int lt   = blockIdx.x;                 // 0..15
  const int pg   = blockIdx.y;                 // 0..1
  const int b    = blockIdx.z;                 // 0..15
  const int tid  = threadIdx.x;
  const int wave = tid >> 6;                   // 0..1
  const int lane = tid & 63;
  const int l0   = lt * LT + lane * 4;         // 4 consecutive l per lane
  const int p0   = __builtin_amdgcn_readfirstlane(pg * (2 * PW) + wave * PW);

  const float* Xb = X + (size_t)b * Cc * Ll + l0;

  float acc[PW][4];
#pragma unroll
  for (int i = 0; i < PW; i++)
#pragma unroll
    for (int k = 0; k < 4; k++) acc[i][k] = 0.0f;

  // one-group-ahead register prefetch: 8 coalesced 1KB wave-loads in flight
  // while 800 FMAs issue (1 wave/SIMD -> ILP must hide HBM latency).
  f32x4 xv[CG];
#pragma unroll
  for (int j = 0; j < CG; j++) xv[j] = *(const f32x4*)(Xb + (size_t)j * Ll);

#pragma unroll 1
  for (int cc = 0; cc < Cc; cc += CG) {
    f32x4 xn[CG];
    const bool more = (cc + CG) < Cc;
    if (more) {
#pragma unroll
      for (int j = 0; j < CG; j++)
        xn[j] = *(const f32x4*)(Xb + (size_t)(cc + CG + j) * Ll);
    }
    // proj[p0+i][cc+j] is wave-uniform -> scalar loads feed v_fmac SGPR
    // operand. Chain per acc[i][k] strictly c-ascending (cc outer, j inner).
#pragma unroll
    for (int i = 0; i < PW; i++) {
      const float* pr = proj + (size_t)(p0 + i) * Cc + cc;
#pragma unroll
      for (int j = 0; j < CG; j++) {
        const float w = pr[j];
        acc[i][0] = __builtin_fmaf(xv[j].x, w, acc[i][0]);
        acc[i][1] = __builtin_fmaf(xv[j].y, w, acc[i][1]);
        acc[i][2] = __builtin_fmaf(xv[j].z, w, acc[i][2]);
        acc[i][3] = __builtin_fmaf(xv[j].w, w, acc[i][3]);
      }
    }
    if (more) {
#pragma unroll
      for (int j = 0; j < CG; j++) xv[j] = xn[j];
    }
  }

  // per-p threshold params; i fully unrolled -> compile-time indices.
  float mnp[PW], dd[PW];
#pragma unroll
  for (int i = 0; i < PW; i++) {
    mnp[i] = mn[p0 + i];
    dd[i]  = __fsub_rn(mx[p0 + i], mnp[i]);   // fl(mx-mn)
  }

  float* ob = set_out + (size_t)b * PQ * Ll + l0;   // + (p*Qq+q)*Ll
  float* cb = cdf + (size_t)b * PQ + (size_t)p0 * Qq;
  const bool lane0 = (lane == 0);

  // q rolled (runtime q never indexes a local array); i fully unrolled.
#pragma unroll 1
  for (int q = 0; q < Qq; q++) {
    const float fr = __fdiv_rn((float)(q + 1), 21.0f);  // fl((q+1)/21)
    int cnt[PW];
#pragma unroll
    for (int i = 0; i < PW; i++) {
      // fl(mn + fl(d*fr)) — separate roundings, no FMA contraction
      const float thr = __fadd_rn(mnp[i], __fmul_rn(dd[i], fr));
      const bool b0 = acc[i][0] < thr;
      const bool b1 = acc[i][1] < thr;
      const bool b2 = acc[i][2] < thr;
      const bool b3 = acc[i][3] < thr;
      f32x4 o;
      o.x = b0 ? 1.0f : 0.0f;
      o.y = b1 ? 1.0f : 0.0f;
      o.z = b2 ? 1.0f : 0.0f;
      o.w = b3 ? 1.0f : 0.0f;
      // streaming, never re-read -> non-temporal (1KB contiguous per wave)
      __builtin_nontemporal_store(
          o, (f32x4*)(ob + ((size_t)(p0 + i) * Qq + q) * Ll));
      // exact per-wave count: 4 ballots (one per sub-l bit)
      cnt[i] = __popcll(__ballot(b0)) + __popcll(__ballot(b1))
             + __popcll(__ballot(b2)) + __popcll(__ballot(b3));
    }
    if (lane0) {
#pragma unroll
      for (int i = 0; i < PW; i++) {
        // exact: every term is a multiple of 2^-12, sums are dyadic <= 1
        atomicAdd(cb + (size_t)i * Qq + q, (float)cnt[i] * (1.0f / (float)Ll));
      }
    }
  }
}

// ---------------------------------------------------------------------------
extern "C" void kernel_launch(void* const* d_in, const int* in_sizes, int n_in,
                              void* d_out, int out_size, void* d_ws, size_t ws_size,
                              hipStream_t stream) {
  const float* X    = (const float*)d_in[0];   // [B,C,L]
  const float* proj = (const float*)d_in[1];   // [P,C]
  const float* mn   = (const float*)d_in[2];   // [P]
  const float* mx   = (const float*)d_in[3];   // [P]

  float* cdf     = (float*)d_out;              // [B, P*Q]
  float* set_out = cdf + (size_t)Bsz * PQ;     // [B, P*Q, L]

  // zero cdf for atomic accumulation (128 KB, ~2 us)
  (void)hipMemsetAsync(cdf, 0, (size_t)Bsz * PQ * sizeof(float), stream);

  csf_fused<<<dim3(Ll / LT, NPG, Bsz), 128, 0, stream>>>(X, proj, mn, mx, cdf,
                                                         set_out);
}

// Round 4
// 602.099 us; speedup vs baseline: 1.4477x; 1.2085x over previous
//
#include <hip/hip_runtime.h>

// Problem constants (from reference)
#define Bsz 16
#define Cc  256
#define Ll  4096
#define Pp  100
#define Qq  20
#define PQ  (Pp * Qq)     // 2000

// Tiling (R0-proven geometry): block = 256 threads = 4 waves; lane owns 4
// consecutive l (f32x4). Block covers LTILE=1024 l's and GP=10 p's -> per
// (p,q) row the block writes 4KB contiguous. 640 blocks = 10 waves/CU, which
// R0 measured at the 6.3 TB/s effective roofline for its traffic.
#define LTILE 1024
#define NLT   (Ll / LTILE)   // 4
#define GP    10
#define NPG   (Pp / GP)      // 10
#define NXCD  8

typedef float f32x4 __attribute__((ext_vector_type(4)));

// ---------------------------------------------------------------------------
// NUMERICS CONTRACT (bit-exact vs numpy fp32 reference, validated R0-R3,
// absmax == 0.0 every round):
//   a[b,p,l]: chain c=0..255 of a = fmaf(X[b,c,l], proj[p,c], a)      [fp32]
//   thr[p,q] = fadd(mn, fmul(fsub(mx,mn), fdiv(q+1, 21)))             [fp32,
//              separate roundings, no contraction]
//   cdf = popcount/4096 (exact dyadic fp32; atomic order irrelevant)
//
// STRUCTURE (R4): timing model over R0-R3 (fill 335us + overhead 80us const)
// shows R0 ran at 6.29 TB/s effective — AT the roofline for its 1195 MB of
// traffic — while R3's low-occupancy rewrite (4 waves/CU) collapsed to
// 2.1 TB/s. So: keep R0's kernel byte-for-byte (geometry, loads, store path,
// atomics) and cut ONLY the traffic. R0's waste: the 10 pg-blocks sharing an
// X tile land on 10 different XCDs (id%8 round-robin) -> every XCD re-fetches
// the tile from HBM (671 MB total vs 67 MB ideal). Swizzle block ids so all
// 10 same-(lt,b) blocks get the SAME residue mod 8 -> same XCD -> co-resident
// lockstep streaming -> 9/10 of X reads become XCD-L2 hits.
//   id = x + 8*k, k = gq*10 + pg, g = gq*8 + x, g = lt + 4*b   (bijective)
// If id%8 is not the XCD mapping this degrades to exactly R0 (perf floor).
// ---------------------------------------------------------------------------
__global__ __launch_bounds__(256) void csf_main(
    const float* __restrict__ X,
    const float* __restrict__ proj,
    const float* __restrict__ mn,
    const float* __restrict__ mx,
    float* __restrict__ cdf,       // d_out[0 .. B*P*Q), zeroed before launch
    float* __restrict__ set_out) { // d_out + B*P*Q, [B][P*Q][L]
    // ---- XCD-co-locating decode of the flat block id ----
    const int id = blockIdx.x;                  // 0..639
    const int x  = id & (NXCD - 1);             // presumed XCD = id % 8
    const int k  = id >> 3;                     // slot within XCD, 0..79
    const int pg = k % NPG;                     // 10 blocks/group: p-group
    const int gq = k / NPG;                     // group slot on this XCD, 0..7
    const int g  = gq * NXCD + x;               // global (lt,b) group, 0..63
    const int lt = g & (NLT - 1);               // 0..3
    const int b  = g >> 2;                      // 0..15

    const int tid = threadIdx.x;
    const int l0  = lt * LTILE + tid * 4;       // 4 consecutive l per lane
    const int p0  = __builtin_amdgcn_readfirstlane(pg * GP);  // wave-uniform

    const float* Xb = X + (size_t)b * Cc * Ll + l0;  // c-th element at +c*Ll

    float acc[GP][4];
#pragma unroll
    for (int i = 0; i < GP; i++)
#pragma unroll
        for (int kk = 0; kk < 4; kk++) acc[i][kk] = 0.0f;

    // fp32 FMA chains, c strictly ascending per accumulator (numpy order).
    // proj index is wave-uniform -> scalar loads; x is a 16B coalesced load.
#pragma unroll 4
    for (int c = 0; c < Cc; c++) {
        const f32x4 xv = *(const f32x4*)(Xb + (size_t)c * Ll);
#pragma unroll
        for (int i = 0; i < GP; i++) {
            const float w = proj[(size_t)(p0 + i) * Cc + c];
            acc[i][0] = __builtin_fmaf(xv.x, w, acc[i][0]);
            acc[i][1] = __builtin_fmaf(xv.y, w, acc[i][1]);
            acc[i][2] = __builtin_fmaf(xv.z, w, acc[i][2]);
            acc[i][3] = __builtin_fmaf(xv.w, w, acc[i][3]);
        }
    }

    // fracs: fl((q+1)/21), IEEE division — same as np.arange/np.float32(21)
    float fr[Qq];
#pragma unroll
    for (int q = 0; q < Qq; q++) fr[q] = __fdiv_rn((float)(q + 1), 21.0f);

    float* ob = set_out + (size_t)b * PQ * Ll + l0;   // + (p*Q+q)*Ll
    const bool lane0 = ((tid & 63) == 0);

#pragma unroll 1
    for (int i = 0; i < GP; i++) {
        const int p = p0 + i;
        const float mnp = mn[p];
        const float mxp = mx[p];
        const float d = __fsub_rn(mxp, mnp);          // fl(mx-mn)
#pragma unroll
        for (int q = 0; q < Qq; q++) {
            // fl(mn + fl(d*frac)) — separate roundings, no FMA contraction
            const float thr = __fadd_rn(mnp, __fmul_rn(d, fr[q]));
            const bool b0 = acc[i][0] < thr;
            const bool b1 = acc[i][1] < thr;
            const bool b2 = acc[i][2] < thr;
            const bool b3 = acc[i][3] < thr;
            f32x4 o;
            o.x = b0 ? 1.0f : 0.0f;
            o.y = b1 ? 1.0f : 0.0f;
            o.z = b2 ? 1.0f : 0.0f;
            o.w = b3 ? 1.0f : 0.0f;
            // streaming, never re-read -> non-temporal (keep L2 for X)
            __builtin_nontemporal_store(o, (f32x4*)(ob + (size_t)(p * Qq + q) * Ll));
            // per-wave count: 4 ballots (one per sub-l bit)
            const int cnt = __popcll(__ballot(b0)) + __popcll(__ballot(b1))
                          + __popcll(__ballot(b2)) + __popcll(__ballot(b3));
            if (lane0) {
                // exact: every term is a multiple of 2^-12, sums are dyadic <=1
                atomicAdd(&cdf[(size_t)b * PQ + p * Qq + q],
                          (float)cnt * (1.0f / (float)Ll));
            }
        }
    }
}

// ---------------------------------------------------------------------------
extern "C" void kernel_launch(void* const* d_in, const int* in_sizes, int n_in,
                              void* d_out, int out_size, void* d_ws, size_t ws_size,
                              hipStream_t stream) {
    const float* X    = (const float*)d_in[0];   // [B,C,L]
    const float* proj = (const float*)d_in[1];   // [P,C]
    const float* mn   = (const float*)d_in[2];   // [P]
    const float* mx   = (const float*)d_in[3];   // [P]

    float* cdf     = (float*)d_out;              // [B, P*Q]
    float* set_out = cdf + (size_t)Bsz * PQ;     // [B, P*Q, L]

    // zero cdf for atomic accumulation (128 KB, ~2 us)
    (void)hipMemsetAsync(cdf, 0, (size_t)Bsz * PQ * sizeof(float), stream);

    csf_main<<<dim3(NLT * NPG * Bsz), 256, 0, stream>>>(X, proj, mn, mx, cdf,
                                                        set_out);
}

// Round 5
// 596.887 us; speedup vs baseline: 1.4603x; 1.0087x over previous
//
#include <hip/hip_runtime.h>

// Problem constants (from reference)
#define Bsz 16
#define Cc  256
#define Ll  4096
#define Pp  100
#define Qq  20
#define PQ  (Pp * Qq)     // 2000

// Tiling (R0-proven geometry): block = 256 threads = 4 waves; lane owns 4
// consecutive l (f32x4). Block covers LTILE=1024 l's and GP=10 p's -> per
// (p,q) row the block writes 4KB contiguous.
#define LTILE 1024
#define NLT   (Ll / LTILE)   // 4
#define GP    10
#define NPG   (Pp / GP)      // 10
#define NXCD  8
#define NSLOT (NLT * 4)      // 16 per-(b,p,q) partial slots (4 lt x 4 waves)
#define CDFN  (Bsz * PQ)     // 32000 cdf entries

typedef float f32x4 __attribute__((ext_vector_type(4)));

// ---------------------------------------------------------------------------
// NUMERICS CONTRACT (bit-exact vs numpy fp32 reference, validated R0-R4,
// absmax == 0.0 every round):
//   a[b,p,l]: chain c=0..255 of a = fmaf(X[b,c,l], proj[p,c], a)      [fp32]
//   thr[p,q] = fadd(mn, fmul(fsub(mx,mn), fdiv(q+1, 21)))             [fp32,
//              separate roundings, no contraction]
//   cdf = popcount/4096: every per-wave partial is k*2^-12 (k<=256), every
//         partial SUM is k*2^-12 with k<=4096 -> exactly representable in
//         fp32 at every step, any association order. Atomic-free reduction
//         is bit-identical to the atomic version.
//
// STRUCTURE (R5): R4's XCD swizzle was a null (602 vs 606) -> X re-reads were
// already L3-absorbed (67MB << 256MB L3), not the bottleneck. Recalibrated
// model (overhead 84us pinned by R2): csf_main ~182us vs ~110-125 modeled
// (compute 25-35 + writes 85). The ~65us gap is attributed to 512K
// device-scope fp32 atomicAdds: cross-XCD RMWs serialize per channel-queue at
// the coherence point (16 RMWs/address x 32K addresses on a 128KB region) and
// don't overlap the nt-store stream. R1's pure store engine with the same
// atomics also capped at 5.1 TB/s (vs fill's 6.3).
// Fix: waves write exact partials non-atomically to d_ws[slot][b][p][q]
// (slot = lt*4+wave, each written exactly once -> no zeroing), tiny second
// kernel sums 16 partials per entry. cdf memset dropped. Everything else
// byte-identical to R4. Atomic fallback kept for ws_size < 2MB.
// ---------------------------------------------------------------------------
template <int MODE>   // 0: atomicAdd into cdf (zeroed)  1: partials into ws
__global__ __launch_bounds__(256) void csf_main(
    const float* __restrict__ X,
    const float* __restrict__ proj,
    const float* __restrict__ mn,
    const float* __restrict__ mx,
    float* __restrict__ cdfout,    // MODE0: cdf [B*PQ]; MODE1: ws [16][B*PQ]
    float* __restrict__ set_out) { // [B][P*Q][L]
    // ---- XCD-co-locating decode (kept from R4; neutral, possibly helps L2)
    const int id = blockIdx.x;                  // 0..639
    const int x  = id & (NXCD - 1);             // presumed XCD = id % 8
    const int k  = id >> 3;                     // slot within XCD, 0..79
    const int pg = k % NPG;                     // p-group
    const int gq = k / NPG;                     // group slot on this XCD
    const int g  = gq * NXCD + x;               // global (lt,b) group, 0..63
    const int lt = g & (NLT - 1);               // 0..3
    const int b  = g >> 2;                      // 0..15

    const int tid  = threadIdx.x;
    const int wave = tid >> 6;                  // 0..3
    const int l0   = lt * LTILE + tid * 4;      // 4 consecutive l per lane
    const int p0   = __builtin_amdgcn_readfirstlane(pg * GP);  // wave-uniform

    const float* Xb = X + (size_t)b * Cc * Ll + l0;  // c-th element at +c*Ll

    float acc[GP][4];
#pragma unroll
    for (int i = 0; i < GP; i++)
#pragma unroll
        for (int kk = 0; kk < 4; kk++) acc[i][kk] = 0.0f;

    // fp32 FMA chains, c strictly ascending per accumulator (numpy order).
    // proj index is wave-uniform -> scalar loads; x is a 16B coalesced load.
#pragma unroll 4
    for (int c = 0; c < Cc; c++) {
        const f32x4 xv = *(const f32x4*)(Xb + (size_t)c * Ll);
#pragma unroll
        for (int i = 0; i < GP; i++) {
            const float w = proj[(size_t)(p0 + i) * Cc + c];
            acc[i][0] = __builtin_fmaf(xv.x, w, acc[i][0]);
            acc[i][1] = __builtin_fmaf(xv.y, w, acc[i][1]);
            acc[i][2] = __builtin_fmaf(xv.z, w, acc[i][2]);
            acc[i][3] = __builtin_fmaf(xv.w, w, acc[i][3]);
        }
    }

    // fracs: fl((q+1)/21), IEEE division — same as np.arange/np.float32(21)
    float fr[Qq];
#pragma unroll
    for (int q = 0; q < Qq; q++) fr[q] = __fdiv_rn((float)(q + 1), 21.0f);

    float* ob = set_out + (size_t)b * PQ * Ll + l0;   // + (p*Q+q)*Ll
    const bool lane0 = ((tid & 63) == 0);
    // MODE1: this wave's private partial row, written exactly once per (p,q)
    float* wsrow = cdfout + (size_t)(lt * 4 + wave) * CDFN + (size_t)b * PQ;

#pragma unroll 1
    for (int i = 0; i < GP; i++) {
        const int p = p0 + i;
        const float mnp = mn[p];
        const float mxp = mx[p];
        const float d = __fsub_rn(mxp, mnp);          // fl(mx-mn)
#pragma unroll
        for (int q = 0; q < Qq; q++) {
            // fl(mn + fl(d*frac)) — separate roundings, no FMA contraction
            const float thr = __fadd_rn(mnp, __fmul_rn(d, fr[q]));
            const bool b0 = acc[i][0] < thr;
            const bool b1 = acc[i][1] < thr;
            const bool b2 = acc[i][2] < thr;
            const bool b3 = acc[i][3] < thr;
            f32x4 o;
            o.x = b0 ? 1.0f : 0.0f;
            o.y = b1 ? 1.0f : 0.0f;
            o.z = b2 ? 1.0f : 0.0f;
            o.w = b3 ? 1.0f : 0.0f;
            // streaming, never re-read -> non-temporal (keep L2 for X)
            __builtin_nontemporal_store(o, (f32x4*)(ob + (size_t)(p * Qq + q) * Ll));
            // per-wave count: 4 ballots (one per sub-l bit)
            const int cnt = __popcll(__ballot(b0)) + __popcll(__ballot(b1))
                          + __popcll(__ballot(b2)) + __popcll(__ballot(b3));
            if (lane0) {
                const float part = (float)cnt * (1.0f / (float)Ll);
                if (MODE == 0) {
                    atomicAdd(&cdfout[(size_t)b * PQ + p * Qq + q], part);
                } else {
                    // plain store, no RMW, re-read by csf_cdf -> keep cached
                    wsrow[(size_t)p * Qq + q] = part;
                }
            }
        }
    }
}

// Sum the 16 exact dyadic partials per cdf entry. 125 blocks x 256 = 32000.
__global__ __launch_bounds__(256) void csf_cdf(
    const float* __restrict__ ws, float* __restrict__ cdf) {
    const int e = blockIdx.x * 256 + threadIdx.x;   // 0..31999
    float s = 0.0f;
#pragma unroll
    for (int t = 0; t < NSLOT; t++)
        s = __fadd_rn(s, ws[(size_t)t * CDFN + e]); // exact at every step
    cdf[e] = s;
}

// ---------------------------------------------------------------------------
extern "C" void kernel_launch(void* const* d_in, const int* in_sizes, int n_in,
                              void* d_out, int out_size, void* d_ws, size_t ws_size,
                              hipStream_t stream) {
    const float* X    = (const float*)d_in[0];   // [B,C,L]
    const float* proj = (const float*)d_in[1];   // [P,C]
    const float* mn   = (const float*)d_in[2];   // [P]
    const float* mx   = (const float*)d_in[3];   // [P]

    float* cdf     = (float*)d_out;              // [B, P*Q]
    float* set_out = cdf + (size_t)Bsz * PQ;     // [B, P*Q, L]

    const size_t ws_need = (size_t)NSLOT * CDFN * sizeof(float);  // 2 MB
    if (d_ws != nullptr && ws_size >= ws_need) {
        float* ws = (float*)d_ws;
        // every ws slot is written exactly once by csf_main<1> -> no zeroing
        csf_main<1><<<dim3(NLT * NPG * Bsz), 256, 0, stream>>>(
            X, proj, mn, mx, ws, set_out);
        csf_cdf<<<dim3(CDFN / 256), 256, 0, stream>>>(ws, cdf);
    } else {
        // fallback: R4-validated atomic path
        (void)hipMemsetAsync(cdf, 0, (size_t)CDFN * sizeof(float), stream);
        csf_main<0><<<dim3(NLT * NPG * Bsz), 256, 0, stream>>>(
            X, proj, mn, mx, cdf, set_out);
    }
}